// Round 5
// baseline (5491.034 us; speedup 1.0000x reference)
//
#include <hip/hip_runtime.h>
#include <stdint.h>
#include <stddef.h>

#define BATCH 128
#define NFRAMES 256
#define EMBED 768
#define RES 2048
#define NCLS 1000
#define NWG 128

typedef __attribute__((ext_vector_type(8))) short bf16x8;
typedef __attribute__((ext_vector_type(4))) float f32x4;
typedef unsigned short u16;

__device__ inline u16 f2bf(float f) {
    union { float f; unsigned u; } v; v.f = f;
    unsigned r = v.u + 0x7FFFu + ((v.u >> 16) & 1u);
    return (u16)(r >> 16);
}
__device__ inline float bf2f(u16 h) {
    union { unsigned u; float f; } v; v.u = ((unsigned)h) << 16;
    return v.f;
}

// ---------------- fp32 -> bf16 convert, vectorized x4 ----------------
__global__ __launch_bounds__(256) void cvt_kernel(const float* __restrict__ in,
                                                  u16* __restrict__ out, int n4) {
    int i = blockIdx.x * blockDim.x + threadIdx.x;
    int stride = gridDim.x * blockDim.x;
    for (; i < n4; i += stride) {
        float4 v = ((const float4*)in)[i];
        ushort4 o;
        o.x = f2bf(v.x); o.y = f2bf(v.y); o.z = f2bf(v.z); o.w = f2bf(v.w);
        ((ushort4*)out)[i] = o;
    }
}

// ---------------- projection: u[t,b,r] = sum_e x[b,t,e] * W_in[r,e] ----------------
__global__ __launch_bounds__(256) void proj_kernel(const u16* __restrict__ xb,
                                                   const u16* __restrict__ win,
                                                   u16* __restrict__ u) {
    int lane = threadIdx.x & 63;
    int w = threadIdx.x >> 6;
    int wm = w >> 1, wn = w & 1;
    int m0 = blockIdx.x * 128 + wm * 64;
    int n0 = blockIdx.y * 128 + wn * 64;
    int lr = lane & 15;
    int lk = (lane >> 4) * 8;

    f32x4 acc[4][4];
#pragma unroll
    for (int i = 0; i < 4; i++)
#pragma unroll
        for (int j = 0; j < 4; j++) acc[i][j] = (f32x4)0.f;

    for (int kk = 0; kk < EMBED; kk += 32) {
        bf16x8 a[4], b[4];
#pragma unroll
        for (int i = 0; i < 4; i++)
            a[i] = *(const bf16x8*)(xb + (size_t)(m0 + i * 16 + lr) * EMBED + kk + lk);
#pragma unroll
        for (int j = 0; j < 4; j++)
            b[j] = *(const bf16x8*)(win + (size_t)(n0 + j * 16 + lr) * EMBED + kk + lk);
#pragma unroll
        for (int i = 0; i < 4; i++)
#pragma unroll
            for (int j = 0; j < 4; j++)
                acc[i][j] = __builtin_amdgcn_mfma_f32_16x16x32_bf16(a[i], b[j], acc[i][j], 0, 0, 0);
    }

    int rowbase = (lane >> 4) * 4;
#pragma unroll
    for (int i = 0; i < 4; i++) {
#pragma unroll
        for (int j = 0; j < 4; j++) {
#pragma unroll
            for (int q = 0; q < 4; q++) {
                int m = m0 + i * 16 + rowbase + q;   // row index = b*NFRAMES + t
                int n = n0 + j * 16 + lr;            // reservoir index
                int bb = m >> 8, tt = m & 255;
                u[((size_t)tt * BATCH + bb) * RES + n] = f2bf(acc[i][j][q]);
            }
        }
    }
}

// ---------------- persistent recurrence ----------------
// 128 WGs x 512 thr. m-half = blockIdx&1 (XCD round-robin preserves parity ->
// all 16 WGs of an XCD share the same 64 state rows in their L2).
// 8 waves K-split 8x256. Reservoir persistent in VGPRs.
// Writes: sc0sc1 write-through (no dirty L2 -> no release fence needed).
// Reads: plain CACHED loads; freshness via one acquire-agent fence (flash
// buffer_inv of L1+L2) per WG per step after the grid barrier.
__global__ __launch_bounds__(512, 1) void recur_kernel(const u16* __restrict__ res,
                                                       const u16* __restrict__ u,
                                                       u16* __restrict__ s0,
                                                       u16* __restrict__ s1,
                                                       unsigned* __restrict__ bar) {
    __shared__ float part[8][64][34];
    const int lane = threadIdx.x & 63;
    const int w = threadIdx.x >> 6;          // K-slice 0..7
    const int m0 = (int)(blockIdx.x & 1) * 64;
    const int n0 = (int)(blockIdx.x >> 1) * 32;
    const int lr = lane & 15;
    const int lk = (lane >> 4) * 8;
    const int rb = (lane >> 4) * 4;
    const int kbase = w * 256;

    // persistent reservoir fragments (cached loads; immutable input)
    bf16x8 bfr[2][8];
#pragma unroll
    for (int jf = 0; jf < 2; jf++)
#pragma unroll
        for (int kk = 0; kk < 8; kk++)
            bfr[jf][kk] = *(const bf16x8*)(res + (size_t)(n0 + jf * 16 + lr) * RES + kbase + kk * 32 + lk);

    // epilogue indices: thread -> (row 0..63, col-quad 0..28)
    const int er = threadIdx.x >> 3;
    const int ec = (threadIdx.x & 7) * 4;
    const size_t gidx = (size_t)(m0 + er) * RES + n0 + ec;

    for (int t = 0; t < NFRAMES; t++) {
        const u16* sin = (t & 1) ? s1 : s0;
        u16* sout = (t & 1) ? s0 : s1;

        // u prefetch (independent of the state produced last step)
        uint2 uv = *(const uint2*)(u + (size_t)t * BATCH * RES + gidx);

        f32x4 acc[4][2];
#pragma unroll
        for (int i = 0; i < 4; i++) { acc[i][0] = (f32x4)0.f; acc[i][1] = (f32x4)0.f; }

#pragma unroll
        for (int i = 0; i < 4; i++) {
            const u16* ap = sin + (size_t)(m0 + i * 16 + lr) * RES + kbase + lk;
            bf16x8 a[8];
#pragma unroll
            for (int kk = 0; kk < 8; kk++)
                a[kk] = *(const bf16x8*)(ap + kk * 32);
#pragma unroll
            for (int kk = 0; kk < 8; kk++) {
                acc[i][0] = __builtin_amdgcn_mfma_f32_16x16x32_bf16(a[kk], bfr[0][kk], acc[i][0], 0, 0, 0);
                acc[i][1] = __builtin_amdgcn_mfma_f32_16x16x32_bf16(a[kk], bfr[1][kk], acc[i][1], 0, 0, 0);
            }
        }

        // K-partials -> LDS (pad 34)
#pragma unroll
        for (int i = 0; i < 4; i++)
#pragma unroll
            for (int jf = 0; jf < 2; jf++)
#pragma unroll
                for (int q = 0; q < 4; q++)
                    part[w][i * 16 + rb + q][jf * 16 + lr] = acc[i][jf][q];
        __syncthreads();

        // single-pass reduce over 8 waves + u add + tanh + packed write-through store
        float sum0 = 0.f, sum1 = 0.f, sum2 = 0.f, sum3 = 0.f;
#pragma unroll
        for (int ww = 0; ww < 8; ww++) {
            const float* pr = &part[ww][er][ec];
            float2 v01 = *(const float2*)pr;
            float2 v23 = *(const float2*)(pr + 2);
            sum0 += v01.x; sum1 += v01.y; sum2 += v23.x; sum3 += v23.y;
        }
        float v0 = tanhf(sum0 + bf2f((u16)(uv.x & 0xFFFF)));
        float v1 = tanhf(sum1 + bf2f((u16)(uv.x >> 16)));
        float v2 = tanhf(sum2 + bf2f((u16)(uv.y & 0xFFFF)));
        float v3 = tanhf(sum3 + bf2f((u16)(uv.y >> 16)));
        uint2 pk;
        pk.x = (unsigned)f2bf(v0) | ((unsigned)f2bf(v1) << 16);
        pk.y = (unsigned)f2bf(v2) | ((unsigned)f2bf(v3) << 16);
        asm volatile("global_store_dwordx2 %0, %1, off sc0 sc1"
                     :: "v"(sout + gidx), "v"(pk) : "memory");

        // drain own stores (write-through -> globally visible at IF), then barrier
        asm volatile("s_waitcnt vmcnt(0)" ::: "memory");
        __syncthreads();
        if (t != NFRAMES - 1) {
            if (threadIdx.x == 0) {
                __hip_atomic_fetch_add(bar + t, 1u, __ATOMIC_RELAXED, __HIP_MEMORY_SCOPE_SYSTEM);
                while (__hip_atomic_load(bar + t, __ATOMIC_RELAXED, __HIP_MEMORY_SCOPE_SYSTEM) < NWG)
                    __builtin_amdgcn_s_sleep(1);
            }
            __syncthreads();
            // acquire: flash-invalidate L1 + this XCD's L2 so the cached state
            // loads of step t+1 refill from the IF (no dirty data exists -> cheap)
            __builtin_amdgcn_fence(__ATOMIC_ACQUIRE, "agent");
        }
    }
}

// ---------------- head: logits[b,c] = sum_r s[b,r]*W_out[c,r] + bias[c] ----------------
__global__ __launch_bounds__(512) void head_kernel(const u16* __restrict__ sin,
                                                   const u16* __restrict__ wout,
                                                   const float* __restrict__ bias,
                                                   float* __restrict__ out) {
    __shared__ float part[8][32][33];
    int lane = threadIdx.x & 63;
    int w = threadIdx.x >> 6;
    int m0 = blockIdx.x * 32;
    int n0 = blockIdx.y * 32;   // over padded 1024
    int k0 = w * 256;
    int lr = lane & 15;
    int lk = (lane >> 4) * 8;

    f32x4 acc[2][2];
#pragma unroll
    for (int i = 0; i < 2; i++)
#pragma unroll
        for (int j = 0; j < 2; j++) acc[i][j] = (f32x4)0.f;

    for (int kk = k0; kk < k0 + 256; kk += 32) {
        bf16x8 a[2], b[2];
#pragma unroll
        for (int i = 0; i < 2; i++)
            a[i] = *(const bf16x8*)(sin + (size_t)(m0 + i * 16 + lr) * RES + kk + lk);
#pragma unroll
        for (int j = 0; j < 2; j++) {
            int row = n0 + j * 16 + lr;
            if (row > NCLS - 1) row = NCLS - 1;  // clamp, result unused
            b[j] = *(const bf16x8*)(wout + (size_t)row * RES + kk + lk);
        }
#pragma unroll
        for (int i = 0; i < 2; i++)
#pragma unroll
            for (int j = 0; j < 2; j++)
                acc[i][j] = __builtin_amdgcn_mfma_f32_16x16x32_bf16(a[i], b[j], acc[i][j], 0, 0, 0);
    }

    int rowbase = (lane >> 4) * 4;
#pragma unroll
    for (int i = 0; i < 2; i++)
#pragma unroll
        for (int j = 0; j < 2; j++)
#pragma unroll
            for (int q = 0; q < 4; q++)
                part[w][i * 16 + rowbase + q][j * 16 + lr] = acc[i][j][q];

    __syncthreads();

    for (int idx = threadIdx.x; idx < 1024; idx += 512) {
        int r = idx >> 5, c = idx & 31;
        float s = 0.f;
#pragma unroll
        for (int ww = 0; ww < 8; ww++) s += part[ww][r][c];
        int cg = n0 + c;
        if (cg < NCLS)
            out[(size_t)(m0 + r) * NCLS + cg] = s + bias[cg];
    }
}

extern "C" void kernel_launch(void* const* d_in, const int* in_sizes, int n_in,
                              void* d_out, int out_size, void* d_ws, size_t ws_size,
                              hipStream_t stream) {
    const float* x_f    = (const float*)d_in[0];  // [128,256,768]
    const float* res_f  = (const float*)d_in[1];  // [2048,2048]
    const float* win_f  = (const float*)d_in[2];  // [2048,768]
    const float* wout_f = (const float*)d_in[3];  // [1000,2048]
    const float* bias   = (const float*)d_in[4];  // [1000]
    float* out = (float*)d_out;

    char* ws = (char*)d_ws;
    size_t off = 0;
    auto alloc = [&](size_t bytes) -> void* {
        void* p = ws + off;
        off += (bytes + 255) & ~(size_t)255;
        return p;
    };
    u16* res_b  = (u16*)alloc((size_t)RES * RES * 2);
    u16* win_b  = (u16*)alloc((size_t)RES * EMBED * 2);
    u16* wout_b = (u16*)alloc((size_t)NCLS * RES * 2);
    u16* x_b    = (u16*)alloc((size_t)BATCH * NFRAMES * EMBED * 2);
    u16* u      = (u16*)alloc((size_t)NFRAMES * BATCH * RES * 2);
    u16* s0     = (u16*)alloc((size_t)BATCH * RES * 2);
    u16* s1     = (u16*)alloc((size_t)BATCH * RES * 2);
    unsigned* bar = (unsigned*)alloc((size_t)NFRAMES * 4);

    // weight / input conversion to bf16
    cvt_kernel<<<dim3(1024), dim3(256), 0, stream>>>(res_f, res_b, RES * RES / 4);
    cvt_kernel<<<dim3(512), dim3(256), 0, stream>>>(win_f, win_b, RES * EMBED / 4);
    cvt_kernel<<<dim3(512), dim3(256), 0, stream>>>(wout_f, wout_b, NCLS * RES / 4);
    cvt_kernel<<<dim3(2048), dim3(256), 0, stream>>>(x_f, x_b, BATCH * NFRAMES * EMBED / 4);

    // state0 = 0, per-step barrier counters = 0 (ws poisoned 0xAA; re-init every call)
    hipMemsetAsync(s0, 0, (size_t)BATCH * RES * 2, stream);
    hipMemsetAsync(bar, 0, (size_t)NFRAMES * 4, stream);

    // u[t,b,r] projection GEMM
    proj_kernel<<<dim3(256, 16), dim3(256), 0, stream>>>(x_b, win_b, u);

    // all 256 recurrence steps in one cooperative launch
    void* args[] = { (void*)&res_b, (void*)&u, (void*)&s0, (void*)&s1, (void*)&bar };
    hipLaunchCooperativeKernel((const void*)recur_kernel, dim3(NWG), dim3(512),
                               args, 0, stream);

    // final state is in s0 (t=255 odd -> wrote s0)
    head_kernel<<<dim3(4, 32), dim3(512), 0, stream>>>(s0, wout_b, bias, out);
}

// Round 6
// 3206.548 us; speedup vs baseline: 1.7124x; 1.7124x over previous
//
#include <hip/hip_runtime.h>
#include <stdint.h>
#include <stddef.h>

#define BATCH 128
#define NFRAMES 256
#define EMBED 768
#define RES 2048
#define NCLS 1000
#define NWG 128

typedef __attribute__((ext_vector_type(8))) short bf16x8;
typedef __attribute__((ext_vector_type(4))) float f32x4;
typedef unsigned short u16;

__device__ inline u16 f2bf(float f) {
    union { float f; unsigned u; } v; v.f = f;
    unsigned r = v.u + 0x7FFFu + ((v.u >> 16) & 1u);
    return (u16)(r >> 16);
}
__device__ inline float bf2f(u16 h) {
    union { unsigned u; float f; } v; v.u = ((unsigned)h) << 16;
    return v.f;
}

// ---------------- fp32 -> bf16 convert, vectorized x4 ----------------
__global__ __launch_bounds__(256) void cvt_kernel(const float* __restrict__ in,
                                                  u16* __restrict__ out, int n4) {
    int i = blockIdx.x * blockDim.x + threadIdx.x;
    int stride = gridDim.x * blockDim.x;
    for (; i < n4; i += stride) {
        float4 v = ((const float4*)in)[i];
        ushort4 o;
        o.x = f2bf(v.x); o.y = f2bf(v.y); o.z = f2bf(v.z); o.w = f2bf(v.w);
        ((ushort4*)out)[i] = o;
    }
}

// ---------------- projection: u[t,b,r] = sum_e x[b,t,e] * W_in[r,e] ----------------
__global__ __launch_bounds__(256) void proj_kernel(const u16* __restrict__ xb,
                                                   const u16* __restrict__ win,
                                                   u16* __restrict__ u) {
    int lane = threadIdx.x & 63;
    int w = threadIdx.x >> 6;
    int wm = w >> 1, wn = w & 1;
    int m0 = blockIdx.x * 128 + wm * 64;
    int n0 = blockIdx.y * 128 + wn * 64;
    int lr = lane & 15;
    int lk = (lane >> 4) * 8;

    f32x4 acc[4][4];
#pragma unroll
    for (int i = 0; i < 4; i++)
#pragma unroll
        for (int j = 0; j < 4; j++) acc[i][j] = (f32x4)0.f;

    for (int kk = 0; kk < EMBED; kk += 32) {
        bf16x8 a[4], b[4];
#pragma unroll
        for (int i = 0; i < 4; i++)
            a[i] = *(const bf16x8*)(xb + (size_t)(m0 + i * 16 + lr) * EMBED + kk + lk);
#pragma unroll
        for (int j = 0; j < 4; j++)
            b[j] = *(const bf16x8*)(win + (size_t)(n0 + j * 16 + lr) * EMBED + kk + lk);
#pragma unroll
        for (int i = 0; i < 4; i++)
#pragma unroll
            for (int j = 0; j < 4; j++)
                acc[i][j] = __builtin_amdgcn_mfma_f32_16x16x32_bf16(a[i], b[j], acc[i][j], 0, 0, 0);
    }

    int rowbase = (lane >> 4) * 4;
#pragma unroll
    for (int i = 0; i < 4; i++) {
#pragma unroll
        for (int j = 0; j < 4; j++) {
#pragma unroll
            for (int q = 0; q < 4; q++) {
                int m = m0 + i * 16 + rowbase + q;   // row index = b*NFRAMES + t
                int n = n0 + j * 16 + lr;            // reservoir index
                int bb = m >> 8, tt = m & 255;
                u[((size_t)tt * BATCH + bb) * RES + n] = f2bf(acc[i][j][q]);
            }
        }
    }
}

// ---------------- persistent recurrence ----------------
// 128 WGs x 512 thr. half = blockIdx&1 (64 batch rows), nblk = blockIdx>>1 (32 cols).
// Batch rows are independent across halves -> TWO disjoint 64-WG barriers.
// Barrier = flag array: arrival is a plain uncached store to own slot (no RMW
// contention); detection is one 64-lane uncached load + __all (fully parallel).
// State exchange: wide uncached (sc0 sc1) loads/stores, coherent at IF, no fences.
// Reservoir fragments persistent in VGPRs.
__global__ __launch_bounds__(512, 1) void recur_kernel(const u16* __restrict__ res,
                                                       const u16* __restrict__ u,
                                                       u16* __restrict__ s0,
                                                       u16* __restrict__ s1,
                                                       unsigned* __restrict__ flags) {
    __shared__ float part[8][64][34];
    const int lane = threadIdx.x & 63;
    const int w = threadIdx.x >> 6;          // K-slice 0..7
    const int half = (int)(blockIdx.x & 1);
    const int nblk = (int)(blockIdx.x >> 1);
    const int m0 = half * 64;
    const int n0 = nblk * 32;
    const int lr = lane & 15;
    const int lk = (lane >> 4) * 8;
    const int rb = (lane >> 4) * 4;
    const int kbase = w * 256;
    unsigned* myflag = flags + half * 64 + nblk;
    unsigned* pollflag = flags + half * 64 + lane;

    // persistent reservoir fragments (cached loads; immutable input)
    bf16x8 bfr[2][8];
#pragma unroll
    for (int jf = 0; jf < 2; jf++)
#pragma unroll
        for (int kk = 0; kk < 8; kk++)
            bfr[jf][kk] = *(const bf16x8*)(res + (size_t)(n0 + jf * 16 + lr) * RES + kbase + kk * 32 + lk);

    // epilogue indices: thread -> (row 0..63, col-quad 0..28)
    const int er = threadIdx.x >> 3;
    const int ec = (threadIdx.x & 7) * 4;
    const size_t gidx = (size_t)(m0 + er) * RES + n0 + ec;

    for (int t = 0; t < NFRAMES; t++) {
        const u16* sin = (t & 1) ? s1 : s0;
        u16* sout = (t & 1) ? s0 : s1;
        const u16* abase = sin + (size_t)(m0 + lr) * RES + kbase + lk;

        // u prefetch (immutable input, cached load, independent of barrier)
        uint2 uv = *(const uint2*)(u + (size_t)t * BATCH * RES + gidx);

        f32x4 acc[4][2];
#pragma unroll
        for (int i = 0; i < 4; i++) { acc[i][0] = (f32x4)0.f; acc[i][1] = (f32x4)0.f; }

        bf16x8 areg[2][8];
        // prologue: issue i=0's 8 A-loads (uncached, wide)
#pragma unroll
        for (int kk = 0; kk < 8; kk++)
            asm volatile("global_load_dwordx4 %0, %1, off sc0 sc1"
                         : "=v"(areg[0][kk]) : "v"(abase + kk * 32));
#pragma unroll
        for (int i = 0; i < 4; i++) {
            if (i < 3) {
                const u16* ab = abase + (size_t)((i + 1) * 16) * RES;
#pragma unroll
                for (int kk = 0; kk < 8; kk++)
                    asm volatile("global_load_dwordx4 %0, %1, off sc0 sc1"
                                 : "=v"(areg[(i + 1) & 1][kk]) : "v"(ab + kk * 32));
                asm volatile("s_waitcnt vmcnt(8)" ::: "memory");
            } else {
                asm volatile("s_waitcnt vmcnt(0)" ::: "memory");
            }
            __builtin_amdgcn_sched_barrier(0);
#pragma unroll
            for (int kk = 0; kk < 8; kk++) {
                acc[i][0] = __builtin_amdgcn_mfma_f32_16x16x32_bf16(areg[i & 1][kk], bfr[0][kk], acc[i][0], 0, 0, 0);
                acc[i][1] = __builtin_amdgcn_mfma_f32_16x16x32_bf16(areg[i & 1][kk], bfr[1][kk], acc[i][1], 0, 0, 0);
            }
        }

        // K-partials -> LDS (pad 34: 2-way bank aliasing only, free)
#pragma unroll
        for (int i = 0; i < 4; i++)
#pragma unroll
            for (int jf = 0; jf < 2; jf++)
#pragma unroll
                for (int q = 0; q < 4; q++)
                    part[w][i * 16 + rb + q][jf * 16 + lr] = acc[i][jf][q];
        __syncthreads();

        // single-pass reduce over 8 waves + u add + tanh + packed write-through store
        float sum0 = 0.f, sum1 = 0.f, sum2 = 0.f, sum3 = 0.f;
#pragma unroll
        for (int ww = 0; ww < 8; ww++) {
            const float* pr = &part[ww][er][ec];
            float2 v01 = *(const float2*)pr;
            float2 v23 = *(const float2*)(pr + 2);
            sum0 += v01.x; sum1 += v01.y; sum2 += v23.x; sum3 += v23.y;
        }
        float v0 = tanhf(sum0 + bf2f((u16)(uv.x & 0xFFFF)));
        float v1 = tanhf(sum1 + bf2f((u16)(uv.x >> 16)));
        float v2 = tanhf(sum2 + bf2f((u16)(uv.y & 0xFFFF)));
        float v3 = tanhf(sum3 + bf2f((u16)(uv.y >> 16)));
        uint2 pk;
        pk.x = (unsigned)f2bf(v0) | ((unsigned)f2bf(v1) << 16);
        pk.y = (unsigned)f2bf(v2) | ((unsigned)f2bf(v3) << 16);
        asm volatile("global_store_dwordx2 %0, %1, off sc0 sc1"
                     :: "v"(sout + gidx), "v"(pk) : "memory");

        // drain own stores (write-through -> visible at IF), then half-scoped
        // flag barrier: store own step-stamp, 64-lane parallel poll, no RMW.
        asm volatile("s_waitcnt vmcnt(0)" ::: "memory");
        __syncthreads();
        if (t != NFRAMES - 1) {
            if (w == 0) {
                if (lane == 0)
                    __hip_atomic_store(myflag, (unsigned)(t + 1), __ATOMIC_RELAXED,
                                       __HIP_MEMORY_SCOPE_SYSTEM);
                unsigned f;
                do {
                    f = __hip_atomic_load(pollflag, __ATOMIC_RELAXED,
                                          __HIP_MEMORY_SCOPE_SYSTEM);
                    if (__all((int)(f >= (unsigned)(t + 1)))) break;
                    __builtin_amdgcn_s_sleep(1);
                } while (1);
            }
            __syncthreads();
        }
    }
}

// ---------------- head: logits[b,c] = sum_r s[b,r]*W_out[c,r] + bias[c] ----------------
__global__ __launch_bounds__(512) void head_kernel(const u16* __restrict__ sin,
                                                   const u16* __restrict__ wout,
                                                   const float* __restrict__ bias,
                                                   float* __restrict__ out) {
    __shared__ float part[8][32][33];
    int lane = threadIdx.x & 63;
    int w = threadIdx.x >> 6;
    int m0 = blockIdx.x * 32;
    int n0 = blockIdx.y * 32;   // over padded 1024
    int k0 = w * 256;
    int lr = lane & 15;
    int lk = (lane >> 4) * 8;

    f32x4 acc[2][2];
#pragma unroll
    for (int i = 0; i < 2; i++)
#pragma unroll
        for (int j = 0; j < 2; j++) acc[i][j] = (f32x4)0.f;

    for (int kk = k0; kk < k0 + 256; kk += 32) {
        bf16x8 a[2], b[2];
#pragma unroll
        for (int i = 0; i < 2; i++)
            a[i] = *(const bf16x8*)(sin + (size_t)(m0 + i * 16 + lr) * RES + kk + lk);
#pragma unroll
        for (int j = 0; j < 2; j++) {
            int row = n0 + j * 16 + lr;
            if (row > NCLS - 1) row = NCLS - 1;  // clamp, result unused
            b[j] = *(const bf16x8*)(wout + (size_t)row * RES + kk + lk);
        }
#pragma unroll
        for (int i = 0; i < 2; i++)
#pragma unroll
            for (int j = 0; j < 2; j++)
                acc[i][j] = __builtin_amdgcn_mfma_f32_16x16x32_bf16(a[i], b[j], acc[i][j], 0, 0, 0);
    }

    int rowbase = (lane >> 4) * 4;
#pragma unroll
    for (int i = 0; i < 2; i++)
#pragma unroll
        for (int j = 0; j < 2; j++)
#pragma unroll
            for (int q = 0; q < 4; q++)
                part[w][i * 16 + rowbase + q][j * 16 + lr] = acc[i][j][q];

    __syncthreads();

    for (int idx = threadIdx.x; idx < 1024; idx += 512) {
        int r = idx >> 5, c = idx & 31;
        float s = 0.f;
#pragma unroll
        for (int ww = 0; ww < 8; ww++) s += part[ww][r][c];
        int cg = n0 + c;
        if (cg < NCLS)
            out[(size_t)(m0 + r) * NCLS + cg] = s + bias[cg];
    }
}

extern "C" void kernel_launch(void* const* d_in, const int* in_sizes, int n_in,
                              void* d_out, int out_size, void* d_ws, size_t ws_size,
                              hipStream_t stream) {
    const float* x_f    = (const float*)d_in[0];  // [128,256,768]
    const float* res_f  = (const float*)d_in[1];  // [2048,2048]
    const float* win_f  = (const float*)d_in[2];  // [2048,768]
    const float* wout_f = (const float*)d_in[3];  // [1000,2048]
    const float* bias   = (const float*)d_in[4];  // [1000]
    float* out = (float*)d_out;

    char* ws = (char*)d_ws;
    size_t off = 0;
    auto alloc = [&](size_t bytes) -> void* {
        void* p = ws + off;
        off += (bytes + 255) & ~(size_t)255;
        return p;
    };
    u16* res_b  = (u16*)alloc((size_t)RES * RES * 2);
    u16* win_b  = (u16*)alloc((size_t)RES * EMBED * 2);
    u16* wout_b = (u16*)alloc((size_t)NCLS * RES * 2);
    u16* x_b    = (u16*)alloc((size_t)BATCH * NFRAMES * EMBED * 2);
    u16* u      = (u16*)alloc((size_t)NFRAMES * BATCH * RES * 2);
    u16* s0     = (u16*)alloc((size_t)BATCH * RES * 2);
    u16* s1     = (u16*)alloc((size_t)BATCH * RES * 2);
    unsigned* flags = (unsigned*)alloc(1024);

    // weight / input conversion to bf16
    cvt_kernel<<<dim3(1024), dim3(256), 0, stream>>>(res_f, res_b, RES * RES / 4);
    cvt_kernel<<<dim3(512), dim3(256), 0, stream>>>(win_f, win_b, RES * EMBED / 4);
    cvt_kernel<<<dim3(512), dim3(256), 0, stream>>>(wout_f, wout_b, NCLS * RES / 4);
    cvt_kernel<<<dim3(2048), dim3(256), 0, stream>>>(x_f, x_b, BATCH * NFRAMES * EMBED / 4);

    // state0 = 0, flags = 0 (ws poisoned 0xAA; re-init every call)
    hipMemsetAsync(s0, 0, (size_t)BATCH * RES * 2, stream);
    hipMemsetAsync(flags, 0, 1024, stream);

    // u[t,b,r] projection GEMM
    proj_kernel<<<dim3(256, 16), dim3(256), 0, stream>>>(x_b, win_b, u);

    // all 256 recurrence steps in one cooperative launch
    void* args[] = { (void*)&res_b, (void*)&u, (void*)&s0, (void*)&s1, (void*)&flags };
    hipLaunchCooperativeKernel((const void*)recur_kernel, dim3(NWG), dim3(512),
                               args, 0, stream);

    // final state is in s0 (t=255 odd -> wrote s0)
    head_kernel<<<dim3(4, 32), dim3(512), 0, stream>>>(s0, wout_b, bias, out);
}